// Round 11
// baseline (388.542 us; speedup 1.0000x reference)
//
#include <hip/hip_runtime.h>

#define NUM_SEG 40000
#define BN_EPS 1e-3f

typedef float f4v __attribute__((ext_vector_type(4)));

// Order-preserving float->uint encoding (for atomicMax over signed floats).
__device__ __forceinline__ unsigned enc_f(float f) {
    unsigned b = __float_as_uint(f);
    return (b & 0x80000000u) ? ~b : (b | 0x80000000u);
}
__device__ __forceinline__ float dec_f(unsigned u) {
    return __uint_as_float((u & 0x80000000u) ? (u ^ 0x80000000u) : ~u);
}

// ---------------- k_prep: zero segmax + detect int64/int32 + convert unq -> int32 ----------------
__global__ __launch_bounds__(256) void k_prep(const void* __restrict__ unq, int N,
                                              int* __restrict__ unq32,
                                              float4* __restrict__ segz, int nseg4) {
    __shared__ int sflag;
    const int tid = threadIdx.x;
    if (tid < 64) {  // wave 0: int64 detection (odd 32-bit words near middle are 0 iff int64)
        const unsigned int* u = (const unsigned int*)unq;
        int w = ((N / 2) | 1) + 2 * tid;
        unsigned v = (w < N) ? u[w] : 0u;
        unsigned long long b = __ballot(v != 0u);
        if (tid == 0) sflag = (b == 0ull) ? 1 : 0;
    }
    __syncthreads();
    const int flag = sflag;
    const long i = (long)blockIdx.x * 256 + tid;
    if (i < nseg4) segz[i] = make_float4(0.f, 0.f, 0.f, 0.f);   // 0 == enc(-inf-ish)
    if (i < N) unq32[i] = flag ? (int)((const long long*)unq)[i] : ((const int*)unq)[i];
}

// ---------------- k1: matmul (W from L1, input from LDS) -> raw x, stats, segmax over RAW x ----------------
// 256 threads, 256-point tile, acc[8][8]. LDS = input tile only (69.6KB) -> 2 blocks/CU, 8 waves/CU.
// W (16KB) is L1-resident; its reads use the VMEM pipe instead of LDS -> LDS instr per FMA drops 3x.
// segment_max commutes with relu(sc*x+sh) (sc>0), so segmax runs on raw x; k4 maps it.
__global__ __launch_bounds__(256, 2) void k1_matmul(
    const float* __restrict__ in, const float* __restrict__ W,
    const int* __restrict__ unq,
    float* __restrict__ out, float* __restrict__ sums, float* __restrict__ sqs,
    unsigned int* __restrict__ segmax, int N, int NBP) {
    __shared__ float sIn[256][68];   // input tile; reused as raw-x buffer
    const int tid = threadIdx.x;
    const int blk = blockIdx.x;
    const long p0 = (long)blk * 256;

    #pragma unroll
    for (int it = 0; it < 16; ++it) {         // stage input tile (4096 float4)
        int f = it * 256 + tid;
        int p = f >> 4;
        long gp = p0 + p;
        f4v v = {0.f, 0.f, 0.f, 0.f};
        if (gp < N) v = __builtin_nontemporal_load(((const f4v*)in) + gp * 16 + (f & 15));
        *(f4v*)&sIn[p][(f & 15) << 2] = v;
    }
    __syncthreads();

    const int pg = tid & 15;                  // point sub-index (16)
    const int cg = (tid >> 4) & 7;            // channel group (8 channels: cg*4.., 32+cg*4..)
    const int ph = tid >> 7;                  // point half (0: rows 0-127, 1: rows 128-255)
    const f4v* __restrict__ W4 = (const f4v*)W;   // W[k][c]: float4 idx k*16 + c/4

    float acc[8][8] = {};
    for (int k0 = 0; k0 < 64; k0 += 4) {
        float4 a[8];
        #pragma unroll
        for (int i = 0; i < 8; ++i) a[i] = *(const float4*)&sIn[ph * 128 + pg + 16 * i][k0];
        #pragma unroll
        for (int kk = 0; kk < 4; ++kk) {
            f4v wlo = W4[(k0 + kk) * 16 + cg];       // L1-resident broadcast
            f4v whi = W4[(k0 + kk) * 16 + 8 + cg];
            #pragma unroll
            for (int i = 0; i < 8; ++i) {
                float av = (&a[i].x)[kk];
                acc[i][0] = fmaf(av, wlo.x, acc[i][0]);
                acc[i][1] = fmaf(av, wlo.y, acc[i][1]);
                acc[i][2] = fmaf(av, wlo.z, acc[i][2]);
                acc[i][3] = fmaf(av, wlo.w, acc[i][3]);
                acc[i][4] = fmaf(av, whi.x, acc[i][4]);
                acc[i][5] = fmaf(av, whi.y, acc[i][5]);
                acc[i][6] = fmaf(av, whi.z, acc[i][6]);
                acc[i][7] = fmaf(av, whi.w, acc[i][7]);
            }
        }
    }

    // per-channel partial sums over this thread's 8 points (tail rows are 0 -> harmless)
    float s[8], q[8];
    #pragma unroll
    for (int j = 0; j < 8; ++j) {
        s[j] = 0.f; q[j] = 0.f;
        #pragma unroll
        for (int i = 0; i < 8; ++i) { s[j] += acc[i][j]; q[j] += acc[i][j] * acc[i][j]; }
    }
    #pragma unroll
    for (int off = 1; off < 16; off <<= 1) {  // reduce over the 16 pg lanes
        #pragma unroll
        for (int j = 0; j < 8; ++j) {
            s[j] += __shfl_xor(s[j], off);
            q[j] += __shfl_xor(q[j], off);
        }
    }
    if (pg == 0) {
        #pragma unroll
        for (int j = 0; j < 8; ++j) {
            int c = (j < 4) ? ((cg << 2) + j) : (32 + (cg << 2) + (j - 4));
            sums[(long)c * NBP + blk * 2 + ph] = s[j];
            sqs [(long)c * NBP + blk * 2 + ph] = q[j];
        }
    }

    // ---- restage raw x into LDS ----
    __syncthreads();   // all matmul reads of sIn done
    #pragma unroll
    for (int i = 0; i < 8; ++i) {
        int p = ph * 128 + pg + 16 * i;
        *(float4*)&sIn[p][cg << 2]        = make_float4(acc[i][0], acc[i][1], acc[i][2], acc[i][3]);
        *(float4*)&sIn[p][32 + (cg << 2)] = make_float4(acc[i][4], acc[i][5], acc[i][6], acc[i][7]);
    }
    __syncthreads();   // x buffer complete

    // coalesced store of raw x -> out[:, :64] (re-read by k4; keep cacheable)
    #pragma unroll
    for (int it = 0; it < 16; ++it) {
        int f = it * 256 + tid;
        int p = f >> 4;
        long gp = p0 + p;
        if (gp < N) ((float4*)out)[gp * 32 + (f & 15)] = *(const float4*)&sIn[p][(f & 15) << 2];
    }

    // per-wave run-compressed segmax over raw x: wave scans 64 consecutive points, lane = channel
    const int wv = tid >> 6;
    const int lane = tid & 63;
    const long gbase = p0 + (long)wv * 64;
    if (gbase < N) {
        const int cnt = (int)min((long)64, (long)N - gbase);
        const int myseg = unq[gbase + ((lane < cnt) ? lane : (cnt - 1))];  // coalesced; shfl-broadcast below
        int cur = __shfl(myseg, 0);
        unsigned runmax = 0u;          // encoded domain; 0 acts as -inf
        for (int r = 0; r < cnt; ++r) {
            int seg = __shfl(myseg, r);
            if (seg != cur) {
                atomicMax(&segmax[(long)cur * 64 + lane], runmax);
                cur = seg; runmax = 0u;
            }
            runmax = max(runmax, enc_f(sIn[wv * 64 + r][lane]));
        }
        atomicMax(&segmax[(long)cur * 64 + lane], runmax);
    }
}

// ---------------- k2: reduce partials -> scale/shift per channel ----------------
__global__ __launch_bounds__(256) void k2_stats(
    const float* __restrict__ sums, const float* __restrict__ sqs,
    const float* __restrict__ gamma, const float* __restrict__ beta,
    float* __restrict__ ss, int N, int NBP) {
    int c = blockIdx.x;
    int tid = threadIdx.x;
    float s = 0.f, q = 0.f;
    for (int i = tid; i < NBP; i += 256) { s += sums[(long)c * NBP + i]; q += sqs[(long)c * NBP + i]; }
    __shared__ float ls[256], lq[256];
    ls[tid] = s; lq[tid] = q;
    __syncthreads();
    for (int off = 128; off > 0; off >>= 1) {
        if (tid < off) { ls[tid] += ls[tid + off]; lq[tid] += lq[tid + off]; }
        __syncthreads();
    }
    if (tid == 0) {
        float mean = ls[0] / (float)N;
        float var  = lq[0] / (float)N - mean * mean;   // biased, matches jnp.var
        float sc = gamma[c] * rsqrtf(var + BN_EPS);
        float sh = beta[c] - mean * sc;
        ss[c] = sc; ss[64 + c] = sh;
    }
}

// ---------------- k4: normalize+ReLU left half in place, gather+normalize right half ----------------
__global__ __launch_bounds__(256) void k4_final(
    float* __restrict__ out, const int* __restrict__ unq,
    const unsigned int* __restrict__ segmax, const float* __restrict__ ss, int N) {
    long t = (long)blockIdx.x * 256 + threadIdx.x;
    long p = t >> 4;
    int qq = (int)(t & 15);
    if (p >= N) return;
    const float4* ss4 = (const float4*)ss;
    float4 sc4 = ss4[qq], sh4 = ss4[16 + qq];

    // left: y = relu(sc*x + sh), in place
    f4v x4 = *((const f4v*)out + p * 32 + qq);
    f4v y4;
    y4.x = fmaxf(fmaf(x4.x, sc4.x, sh4.x), 0.f);
    y4.y = fmaxf(fmaf(x4.y, sc4.y, sh4.y), 0.f);
    y4.z = fmaxf(fmaf(x4.z, sc4.z, sh4.z), 0.f);
    y4.w = fmaxf(fmaf(x4.w, sc4.w, sh4.w), 0.f);
    __builtin_nontemporal_store(y4, (f4v*)out + p * 32 + qq);

    // right: decode segmax(raw x), apply same monotone map (exact: same fma as the argmax point)
    int seg = unq[p];
    uint4 m4 = ((const uint4*)segmax)[(long)seg * 16 + qq];
    f4v z4;
    z4.x = fmaxf(fmaf(dec_f(m4.x), sc4.x, sh4.x), 0.f);
    z4.y = fmaxf(fmaf(dec_f(m4.y), sc4.y, sh4.y), 0.f);
    z4.z = fmaxf(fmaf(dec_f(m4.z), sc4.z, sh4.z), 0.f);
    z4.w = fmaxf(fmaf(dec_f(m4.w), sc4.w, sh4.w), 0.f);
    __builtin_nontemporal_store(z4, (f4v*)out + p * 32 + 16 + qq);
}

extern "C" void kernel_launch(void* const* d_in, const int* in_sizes, int n_in,
                              void* d_out, int out_size, void* d_ws, size_t ws_size,
                              hipStream_t stream) {
    const float* in    = (const float*)d_in[0];
    const float* W     = (const float*)d_in[1];
    const float* gamma = (const float*)d_in[2];
    const float* beta  = (const float*)d_in[3];
    const void*  unq   = d_in[4];
    float* out = (float*)d_out;

    const int N   = in_sizes[0] / 64;
    const int NB  = (N + 255) / 256;
    const int NBP = 2 * NB;

    char* ws = (char*)d_ws;
    unsigned int* segmax = (unsigned int*)ws;                    // 10.24 MB (encoded floats)
    size_t off = (size_t)NUM_SEG * 64 * 4;
    float* sums = (float*)(ws + off); off += (size_t)64 * NBP * 4;
    float* sqs  = (float*)(ws + off); off += (size_t)64 * NBP * 4;
    float* ss   = (float*)(ws + off); off += 512;
    int*   unq32= (int*)(ws + off);   off += (size_t)N * 4;

    const int n4 = NUM_SEG * 64 / 4;
    const int gprep = max((N + 255) / 256, (n4 + 255) / 256);
    k_prep<<<gprep, 256, 0, stream>>>(unq, N, unq32, (float4*)segmax, n4);
    k1_matmul<<<NB, 256, 0, stream>>>(in, W, unq32, out, sums, sqs, segmax, N, NBP);
    k2_stats<<<64, 256, 0, stream>>>(sums, sqs, gamma, beta, ss, N, NBP);
    k4_final<<<(int)(((long)N * 16 + 255) / 256), 256, 0, stream>>>(out, unq32, segmax, ss, N);
}

// Round 12
// 354.321 us; speedup vs baseline: 1.0966x; 1.0966x over previous
//
#include <hip/hip_runtime.h>

#define NUM_SEG 40000
#define BN_EPS 1e-3f

typedef float f4v __attribute__((ext_vector_type(4)));
typedef short bf16x8 __attribute__((ext_vector_type(8)));
typedef float f32x4 __attribute__((ext_vector_type(4)));

// Order-preserving float->uint encoding (for atomicMax over signed floats).
__device__ __forceinline__ unsigned enc_f(float f) {
    unsigned b = __float_as_uint(f);
    return (b & 0x80000000u) ? ~b : (b | 0x80000000u);
}
__device__ __forceinline__ float dec_f(unsigned u) {
    return __uint_as_float((u & 0x80000000u) ? (u ^ 0x80000000u) : ~u);
}
// bf16 round-to-nearest-even
__device__ __forceinline__ unsigned short f2bf(float f) {
    unsigned b = __float_as_uint(f);
    b += 0x7fffu + ((b >> 16) & 1u);
    return (unsigned short)(b >> 16);
}
__device__ __forceinline__ float bf2f(unsigned short u) {
    return __uint_as_float(((unsigned)u) << 16);
}

// ---------------- k_prep: zero segmax + detect int64/int32 + convert unq -> int32 ----------------
__global__ __launch_bounds__(256) void k_prep(const void* __restrict__ unq, int N,
                                              int* __restrict__ unq32,
                                              float4* __restrict__ segz, int nseg4) {
    __shared__ int sflag;
    const int tid = threadIdx.x;
    if (tid < 64) {
        const unsigned int* u = (const unsigned int*)unq;
        int w = ((N / 2) | 1) + 2 * tid;
        unsigned v = (w < N) ? u[w] : 0u;
        unsigned long long b = __ballot(v != 0u);
        if (tid == 0) sflag = (b == 0ull) ? 1 : 0;
    }
    __syncthreads();
    const int flag = sflag;
    const long i = (long)blockIdx.x * 256 + tid;
    if (i < nseg4) segz[i] = make_float4(0.f, 0.f, 0.f, 0.f);   // 0 == enc(-inf)
    if (i < N) unq32[i] = flag ? (int)((const long long*)unq)[i] : ((const int*)unq)[i];
}

// ---------------- k1: MFMA bf16-split matmul -> raw x, stats, segmax over RAW x ----------------
// 256 thr, 128-pt tile. A (pts x 64) and Wt (out-ch x 64) staged as bf16 hi/lo in LDS with
// XOR-swizzle (byte ^ ((row&7)<<4)) to kill stride-128B bank conflicts on frag reads.
// x = ahi@Whi + ahi@Wlo + alo@Whi (fp32 acc; dropped lo@lo term ~1e-4 rel).
// MFMA 16x16x32: A lane layout row=l&15, k=(l>>4)*8+j; B col=l&15, k likewise;
// C/D col=lane&15, row=(lane>>4)*4+reg [m89].
__global__ __launch_bounds__(256, 3) void k1_mfma(
    const float* __restrict__ in, const float* __restrict__ W,
    const int* __restrict__ unq,
    float* __restrict__ out, float* __restrict__ sums, float* __restrict__ sqs,
    unsigned int* __restrict__ segmax, int N, int NBS) {
    __shared__ __align__(16) char lds[49152];
    // bytes [0,16384): Ahi[128][64]bf16 swz   [16384,32768): Alo
    // [32768,40960): Whi_t[64][64]bf16 swz    [40960,49152): Wlo_t
    // overlay after barrier: xbuf = (float*)lds, [128][68] f32
    const int tid = threadIdx.x;
    const int blk = blockIdx.x;
    const long p0 = (long)blk * 128;
    const int wv = tid >> 6;
    const int l  = tid & 63;

    // --- stage Wt (transposed, split): wave wv covers k rows wv*16..+15; lane l = out-ch n ---
    {
        unsigned short hb[16], lb[16];
        #pragma unroll
        for (int kk = 0; kk < 16; ++kk) {
            float f = W[(wv * 16 + kk) * 64 + l];      // coalesced 256B row per kk
            unsigned short h = f2bf(f);
            hb[kk] = h;
            lb[kk] = f2bf(f - bf2f(h));
        }
        #pragma unroll
        for (int cc = 0; cc < 4; ++cc) {
            int cb = wv * 32 + cc * 8;                 // byte col within row
            int addr = l * 128 + (cb ^ ((l & 7) << 4));
            *(ushort4*)(lds + 32768 + addr) = make_ushort4(hb[cc*4], hb[cc*4+1], hb[cc*4+2], hb[cc*4+3]);
            *(ushort4*)(lds + 40960 + addr) = make_ushort4(lb[cc*4], lb[cc*4+1], lb[cc*4+2], lb[cc*4+3]);
        }
    }
    // --- stage A (split): 2048 float4 over 8 iters ---
    #pragma unroll
    for (int it = 0; it < 8; ++it) {
        int f = it * 256 + tid;
        int p = f >> 4;
        long gp = p0 + p;
        float4 v = make_float4(0.f, 0.f, 0.f, 0.f);
        if (gp < N) v = ((const float4*)in)[gp * 16 + (f & 15)];
        unsigned short hx = f2bf(v.x), hy = f2bf(v.y), hz = f2bf(v.z), hw = f2bf(v.w);
        int cb = (f & 15) * 8;
        int addr = p * 128 + (cb ^ ((p & 7) << 4));
        *(ushort4*)(lds + addr)         = make_ushort4(hx, hy, hz, hw);
        *(ushort4*)(lds + 16384 + addr) = make_ushort4(f2bf(v.x - bf2f(hx)), f2bf(v.y - bf2f(hy)),
                                                       f2bf(v.z - bf2f(hz)), f2bf(v.w - bf2f(hw)));
    }
    __syncthreads();

    // --- MFMA: wave wv owns points wv*32..+31 (rows), all 64 channels ---
    const int lr = l & 15;
    const int lg = l >> 4;
    f32x4 acc[2][4] = {};
    #pragma unroll
    for (int ks = 0; ks < 2; ++ks) {
        const int cb = ks * 64 + lg * 16;
        bf16x8 ah[2], al[2], bh[4], bl[4];
        #pragma unroll
        for (int mt = 0; mt < 2; ++mt) {
            int r = wv * 32 + mt * 16 + lr;
            int addr = r * 128 + (cb ^ ((r & 7) << 4));
            ah[mt] = *(const bf16x8*)(lds + addr);
            al[mt] = *(const bf16x8*)(lds + 16384 + addr);
        }
        #pragma unroll
        for (int nt = 0; nt < 4; ++nt) {
            int n = nt * 16 + lr;
            int addr = n * 128 + (cb ^ ((n & 7) << 4));
            bh[nt] = *(const bf16x8*)(lds + 32768 + addr);
            bl[nt] = *(const bf16x8*)(lds + 40960 + addr);
        }
        #pragma unroll
        for (int mt = 0; mt < 2; ++mt)
            #pragma unroll
            for (int nt = 0; nt < 4; ++nt) {
                acc[mt][nt] = __builtin_amdgcn_mfma_f32_16x16x32_bf16(ah[mt], bh[nt], acc[mt][nt], 0, 0, 0);
                acc[mt][nt] = __builtin_amdgcn_mfma_f32_16x16x32_bf16(ah[mt], bl[nt], acc[mt][nt], 0, 0, 0);
                acc[mt][nt] = __builtin_amdgcn_mfma_f32_16x16x32_bf16(al[mt], bh[nt], acc[mt][nt], 0, 0, 0);
            }
    }

    // --- stats: channel c = nt*16 + lr; sum over this wave's 32 points ---
    {
        float s[4], q[4];
        #pragma unroll
        for (int nt = 0; nt < 4; ++nt) {
            s[nt] = 0.f; q[nt] = 0.f;
            #pragma unroll
            for (int mt = 0; mt < 2; ++mt)
                #pragma unroll
                for (int r = 0; r < 4; ++r) {
                    float x = acc[mt][nt][r];
                    s[nt] += x; q[nt] += x * x;
                }
        }
        #pragma unroll
        for (int off = 16; off < 64; off <<= 1) {   // sum lanes sharing lr
            #pragma unroll
            for (int nt = 0; nt < 4; ++nt) {
                s[nt] += __shfl_xor(s[nt], off);
                q[nt] += __shfl_xor(q[nt], off);
            }
        }
        if (l < 16) {
            #pragma unroll
            for (int nt = 0; nt < 4; ++nt) {
                int c = nt * 16 + l;
                sums[(long)c * NBS + blk * 4 + wv] = s[nt];
                sqs [(long)c * NBS + blk * 4 + wv] = q[nt];
            }
        }
    }

    // --- restage raw x into xbuf (overlays A/W tiles) ---
    __syncthreads();   // all frag reads done
    float* xbuf = (float*)lds;
    #pragma unroll
    for (int mt = 0; mt < 2; ++mt)
        #pragma unroll
        for (int nt = 0; nt < 4; ++nt)
            #pragma unroll
            for (int r = 0; r < 4; ++r)
                xbuf[(wv * 32 + mt * 16 + lg * 4 + r) * 68 + nt * 16 + lr] = acc[mt][nt][r];
    __syncthreads();

    // --- coalesced store raw x -> out[:, :64] ---
    #pragma unroll
    for (int it = 0; it < 8; ++it) {
        int f = it * 256 + tid;
        int p = f >> 4;
        long gp = p0 + p;
        if (gp < N) ((float4*)out)[gp * 32 + (f & 15)] = *(const float4*)&xbuf[p * 68 + (f & 15) * 4];
    }

    // --- per-wave run-compressed segmax over raw x: 32 consecutive points, lane = channel ---
    const long gbase = p0 + (long)wv * 32;
    if (gbase < N) {
        const int cnt = (int)min((long)32, (long)N - gbase);
        const int myseg = unq[gbase + ((l < cnt) ? l : (cnt - 1))];
        int cur = __shfl(myseg, 0);
        unsigned runmax = 0u;
        for (int r = 0; r < cnt; ++r) {
            int seg = __shfl(myseg, r);
            if (seg != cur) {
                atomicMax(&segmax[(long)cur * 64 + l], runmax);
                cur = seg; runmax = 0u;
            }
            runmax = max(runmax, enc_f(xbuf[(wv * 32 + r) * 68 + l]));
        }
        atomicMax(&segmax[(long)cur * 64 + l], runmax);
    }
}

// ---------------- k2: reduce partials -> scale/shift per channel ----------------
__global__ __launch_bounds__(256) void k2_stats(
    const float* __restrict__ sums, const float* __restrict__ sqs,
    const float* __restrict__ gamma, const float* __restrict__ beta,
    float* __restrict__ ss, int N, int NBS) {
    int c = blockIdx.x;
    int tid = threadIdx.x;
    float s = 0.f, q = 0.f;
    for (int i = tid; i < NBS; i += 256) { s += sums[(long)c * NBS + i]; q += sqs[(long)c * NBS + i]; }
    __shared__ float ls[256], lq[256];
    ls[tid] = s; lq[tid] = q;
    __syncthreads();
    for (int off = 128; off > 0; off >>= 1) {
        if (tid < off) { ls[tid] += ls[tid + off]; lq[tid] += lq[tid + off]; }
        __syncthreads();
    }
    if (tid == 0) {
        float mean = ls[0] / (float)N;
        float var  = lq[0] / (float)N - mean * mean;   // biased, matches jnp.var
        float sc = gamma[c] * rsqrtf(var + BN_EPS);
        float sh = beta[c] - mean * sc;
        ss[c] = sc; ss[64 + c] = sh;
    }
}

// ---------------- k4: normalize+ReLU left half in place, gather+normalize right half ----------------
__global__ __launch_bounds__(256) void k4_final(
    float* __restrict__ out, const int* __restrict__ unq,
    const unsigned int* __restrict__ segmax, const float* __restrict__ ss, int N) {
    long t = (long)blockIdx.x * 256 + threadIdx.x;
    long p = t >> 4;
    int qq = (int)(t & 15);
    if (p >= N) return;
    const float4* ss4 = (const float4*)ss;
    float4 sc4 = ss4[qq], sh4 = ss4[16 + qq];

    f4v x4 = *((const f4v*)out + p * 32 + qq);
    f4v y4;
    y4.x = fmaxf(fmaf(x4.x, sc4.x, sh4.x), 0.f);
    y4.y = fmaxf(fmaf(x4.y, sc4.y, sh4.y), 0.f);
    y4.z = fmaxf(fmaf(x4.z, sc4.z, sh4.z), 0.f);
    y4.w = fmaxf(fmaf(x4.w, sc4.w, sh4.w), 0.f);
    __builtin_nontemporal_store(y4, (f4v*)out + p * 32 + qq);

    int seg = unq[p];
    uint4 m4 = ((const uint4*)segmax)[(long)seg * 16 + qq];
    f4v z4;
    z4.x = fmaxf(fmaf(dec_f(m4.x), sc4.x, sh4.x), 0.f);
    z4.y = fmaxf(fmaf(dec_f(m4.y), sc4.y, sh4.y), 0.f);
    z4.z = fmaxf(fmaf(dec_f(m4.z), sc4.z, sh4.z), 0.f);
    z4.w = fmaxf(fmaf(dec_f(m4.w), sc4.w, sh4.w), 0.f);
    __builtin_nontemporal_store(z4, (f4v*)out + p * 32 + 16 + qq);
}

extern "C" void kernel_launch(void* const* d_in, const int* in_sizes, int n_in,
                              void* d_out, int out_size, void* d_ws, size_t ws_size,
                              hipStream_t stream) {
    const float* in    = (const float*)d_in[0];
    const float* W     = (const float*)d_in[1];
    const float* gamma = (const float*)d_in[2];
    const float* beta  = (const float*)d_in[3];
    const void*  unq   = d_in[4];
    float* out = (float*)d_out;

    const int N   = in_sizes[0] / 64;
    const int NB  = (N + 127) / 128;
    const int NBS = 4 * NB;

    char* ws = (char*)d_ws;
    unsigned int* segmax = (unsigned int*)ws;                    // 10.24 MB (encoded floats)
    size_t off = (size_t)NUM_SEG * 64 * 4;
    float* sums = (float*)(ws + off); off += (size_t)64 * NBS * 4;
    float* sqs  = (float*)(ws + off); off += (size_t)64 * NBS * 4;
    float* ss   = (float*)(ws + off); off += 512;
    int*   unq32= (int*)(ws + off);   off += (size_t)N * 4;

    const int n4 = NUM_SEG * 64 / 4;
    const int gprep = max((N + 255) / 256, (n4 + 255) / 256);
    k_prep<<<gprep, 256, 0, stream>>>(unq, N, unq32, (float4*)segmax, n4);
    k1_mfma<<<NB, 256, 0, stream>>>(in, W, unq32, out, sums, sqs, segmax, N, NBS);
    k2_stats<<<64, 256, 0, stream>>>(sums, sqs, gamma, beta, ss, N, NBS);
    k4_final<<<(int)(((long)N * 16 + 255) / 256), 256, 0, stream>>>(out, unq32, segmax, ss, N);
}

// Round 14
// 340.694 us; speedup vs baseline: 1.1404x; 1.0400x over previous
//
#include <hip/hip_runtime.h>

#define NUM_SEG 40000
#define BN_EPS 1e-3f

typedef float f4v __attribute__((ext_vector_type(4)));
typedef short bf16x8 __attribute__((ext_vector_type(8)));
typedef float f32x4 __attribute__((ext_vector_type(4)));

// Order-preserving float->uint encoding (for atomicMax over signed floats).
__device__ __forceinline__ unsigned enc_f(float f) {
    unsigned b = __float_as_uint(f);
    return (b & 0x80000000u) ? ~b : (b | 0x80000000u);
}
__device__ __forceinline__ float dec_f(unsigned u) {
    return __uint_as_float((u & 0x80000000u) ? (u ^ 0x80000000u) : ~u);
}
// bf16 round-to-nearest-even
__device__ __forceinline__ unsigned short f2bf(float f) {
    unsigned b = __float_as_uint(f);
    b += 0x7fffu + ((b >> 16) & 1u);
    return (unsigned short)(b >> 16);
}
__device__ __forceinline__ float bf2f(unsigned short u) {
    return __uint_as_float(((unsigned)u) << 16);
}

// ---------------- k_prep: zero segmax + detect int64/int32 + convert unq -> int32 ----------------
__global__ __launch_bounds__(256) void k_prep(const void* __restrict__ unq, int N,
                                              int* __restrict__ unq32,
                                              float4* __restrict__ segz, int nseg4) {
    __shared__ int sflag;
    const int tid = threadIdx.x;
    if (tid < 64) {
        const unsigned int* u = (const unsigned int*)unq;
        int w = ((N / 2) | 1) + 2 * tid;
        unsigned v = (w < N) ? u[w] : 0u;
        unsigned long long b = __ballot(v != 0u);
        if (tid == 0) sflag = (b == 0ull) ? 1 : 0;
    }
    __syncthreads();
    const int flag = sflag;
    const long i = (long)blockIdx.x * 256 + tid;
    if (i < nseg4) segz[i] = make_float4(0.f, 0.f, 0.f, 0.f);   // 0 == enc(-inf)
    if (i < N) unq32[i] = flag ? (int)((const long long*)unq)[i] : ((const int*)unq)[i];
}

// ---------------- k1: MFMA bf16-split matmul -> raw x to DENSE xtmp, stats, segmax over RAW x ----------------
// 256 thr, 128-pt tile, LDS 48KB -> 3 blocks/CU. x = ahi@Whi + ahi@Wlo + alo@Whi (fp32 acc).
// All global streams dense: in read sequential, xtmp write sequential.
__global__ __launch_bounds__(256, 3) void k1_mfma(
    const float* __restrict__ in, const float* __restrict__ W,
    const int* __restrict__ unq,
    float* __restrict__ xtmp, float* __restrict__ sums, float* __restrict__ sqs,
    unsigned int* __restrict__ segmax, int N, int NBS) {
    __shared__ __align__(16) char lds[49152];
    // bytes [0,16384): Ahi[128][64]bf16 swz   [16384,32768): Alo
    // [32768,40960): Whi_t[64][64]bf16 swz    [40960,49152): Wlo_t
    // overlay after barrier: xbuf = (float*)lds, [128][68] f32
    const int tid = threadIdx.x;
    const int blk = blockIdx.x;
    const long p0 = (long)blk * 128;
    const int wv = tid >> 6;
    const int l  = tid & 63;

    // --- stage Wt (transposed, split): wave wv covers k rows wv*16..+15; lane l = out-ch n ---
    {
        unsigned short hb[16], lb[16];
        #pragma unroll
        for (int kk = 0; kk < 16; ++kk) {
            float f = W[(wv * 16 + kk) * 64 + l];      // coalesced 256B row per kk
            unsigned short h = f2bf(f);
            hb[kk] = h;
            lb[kk] = f2bf(f - bf2f(h));
        }
        #pragma unroll
        for (int cc = 0; cc < 4; ++cc) {
            int cb = wv * 32 + cc * 8;                 // byte col within row
            int addr = l * 128 + (cb ^ ((l & 7) << 4));
            *(ushort4*)(lds + 32768 + addr) = make_ushort4(hb[cc*4], hb[cc*4+1], hb[cc*4+2], hb[cc*4+3]);
            *(ushort4*)(lds + 40960 + addr) = make_ushort4(lb[cc*4], lb[cc*4+1], lb[cc*4+2], lb[cc*4+3]);
        }
    }
    // --- stage A (split): 2048 float4 over 8 iters ---
    #pragma unroll
    for (int it = 0; it < 8; ++it) {
        int f = it * 256 + tid;
        int p = f >> 4;
        long gp = p0 + p;
        float4 v = make_float4(0.f, 0.f, 0.f, 0.f);
        if (gp < N) v = ((const float4*)in)[gp * 16 + (f & 15)];
        unsigned short hx = f2bf(v.x), hy = f2bf(v.y), hz = f2bf(v.z), hw = f2bf(v.w);
        int cb = (f & 15) * 8;
        int addr = p * 128 + (cb ^ ((p & 7) << 4));
        *(ushort4*)(lds + addr)         = make_ushort4(hx, hy, hz, hw);
        *(ushort4*)(lds + 16384 + addr) = make_ushort4(f2bf(v.x - bf2f(hx)), f2bf(v.y - bf2f(hy)),
                                                       f2bf(v.z - bf2f(hz)), f2bf(v.w - bf2f(hw)));
    }
    __syncthreads();

    // --- MFMA: wave wv owns points wv*32..+31 (rows), all 64 channels ---
    const int lr = l & 15;
    const int lg = l >> 4;
    f32x4 acc[2][4] = {};
    #pragma unroll
    for (int ks = 0; ks < 2; ++ks) {
        const int cb = ks * 64 + lg * 16;
        bf16x8 ah[2], al[2], bh[4], bl[4];
        #pragma unroll
        for (int mt = 0; mt < 2; ++mt) {
            int r = wv * 32 + mt * 16 + lr;
            int addr = r * 128 + (cb ^ ((r & 7) << 4));
            ah[mt] = *(const bf16x8*)(lds + addr);
            al[mt] = *(const bf16x8*)(lds + 16384 + addr);
        }
        #pragma unroll
        for (int nt = 0; nt < 4; ++nt) {
            int n = nt * 16 + lr;
            int addr = n * 128 + (cb ^ ((n & 7) << 4));
            bh[nt] = *(const bf16x8*)(lds + 32768 + addr);
            bl[nt] = *(const bf16x8*)(lds + 40960 + addr);
        }
        #pragma unroll
        for (int mt = 0; mt < 2; ++mt)
            #pragma unroll
            for (int nt = 0; nt < 4; ++nt) {
                acc[mt][nt] = __builtin_amdgcn_mfma_f32_16x16x32_bf16(ah[mt], bh[nt], acc[mt][nt], 0, 0, 0);
                acc[mt][nt] = __builtin_amdgcn_mfma_f32_16x16x32_bf16(ah[mt], bl[nt], acc[mt][nt], 0, 0, 0);
                acc[mt][nt] = __builtin_amdgcn_mfma_f32_16x16x32_bf16(al[mt], bh[nt], acc[mt][nt], 0, 0, 0);
            }
    }

    // --- stats: channel c = nt*16 + lr; sum over this wave's 32 points ---
    {
        float s[4], q[4];
        #pragma unroll
        for (int nt = 0; nt < 4; ++nt) {
            s[nt] = 0.f; q[nt] = 0.f;
            #pragma unroll
            for (int mt = 0; mt < 2; ++mt)
                #pragma unroll
                for (int r = 0; r < 4; ++r) {
                    float x = acc[mt][nt][r];
                    s[nt] += x; q[nt] += x * x;
                }
        }
        #pragma unroll
        for (int off = 16; off < 64; off <<= 1) {   // sum lanes sharing lr
            #pragma unroll
            for (int nt = 0; nt < 4; ++nt) {
                s[nt] += __shfl_xor(s[nt], off);
                q[nt] += __shfl_xor(q[nt], off);
            }
        }
        if (l < 16) {
            #pragma unroll
            for (int nt = 0; nt < 4; ++nt) {
                int c = nt * 16 + l;
                sums[(long)c * NBS + blk * 4 + wv] = s[nt];
                sqs [(long)c * NBS + blk * 4 + wv] = q[nt];
            }
        }
    }

    // --- restage raw x into xbuf (overlays A/W tiles) ---
    __syncthreads();   // all frag reads done
    float* xbuf = (float*)lds;
    #pragma unroll
    for (int mt = 0; mt < 2; ++mt)
        #pragma unroll
        for (int nt = 0; nt < 4; ++nt)
            #pragma unroll
            for (int r = 0; r < 4; ++r)
                xbuf[(wv * 32 + mt * 16 + lg * 4 + r) * 68 + nt * 16 + lr] = acc[mt][nt][r];
    __syncthreads();

    // --- DENSE store raw x -> xtmp[p][0..64) (fully sequential stream) ---
    #pragma unroll
    for (int it = 0; it < 8; ++it) {
        int f = it * 256 + tid;
        int p = f >> 4;
        long gp = p0 + p;
        if (gp < N)
            __builtin_nontemporal_store(*(const f4v*)&xbuf[p * 68 + (f & 15) * 4],
                                        (f4v*)xtmp + gp * 16 + (f & 15));
    }

    // --- per-wave run-compressed segmax over raw x: 32 consecutive points, lane = channel ---
    const long gbase = p0 + (long)wv * 32;
    if (gbase < N) {
        const int cnt = (int)min((long)32, (long)N - gbase);
        const int myseg = unq[gbase + ((l < cnt) ? l : (cnt - 1))];
        int cur = __shfl(myseg, 0);
        unsigned runmax = 0u;
        for (int r = 0; r < cnt; ++r) {
            int seg = __shfl(myseg, r);
            if (seg != cur) {
                atomicMax(&segmax[(long)cur * 64 + l], runmax);
                cur = seg; runmax = 0u;
            }
            runmax = max(runmax, enc_f(xbuf[(wv * 32 + r) * 68 + l]));
        }
        atomicMax(&segmax[(long)cur * 64 + l], runmax);
    }
}

// ---------------- k2: reduce partials -> scale/shift per channel ----------------
__global__ __launch_bounds__(256) void k2_stats(
    const float* __restrict__ sums, const float* __restrict__ sqs,
    const float* __restrict__ gamma, const float* __restrict__ beta,
    float* __restrict__ ss, int N, int NBS) {
    int c = blockIdx.x;
    int tid = threadIdx.x;
    float s = 0.f, q = 0.f;
    for (int i = tid; i < NBS; i += 256) { s += sums[(long)c * NBS + i]; q += sqs[(long)c * NBS + i]; }
    __shared__ float ls[256], lq[256];
    ls[tid] = s; lq[tid] = q;
    __syncthreads();
    for (int off = 128; off > 0; off >>= 1) {
        if (tid < off) { ls[tid] += ls[tid + off]; lq[tid] += lq[tid + off]; }
        __syncthreads();
    }
    if (tid == 0) {
        float mean = ls[0] / (float)N;
        float var  = lq[0] / (float)N - mean * mean;   // biased, matches jnp.var
        float sc = gamma[c] * rsqrtf(var + BN_EPS);
        float sh = beta[c] - mean * sc;
        ss[c] = sc; ss[64 + c] = sh;
    }
}

// ---------------- k4: read dense xtmp, write BOTH halves of out dense ----------------
__global__ __launch_bounds__(256) void k4_final(
    float* __restrict__ out, const int* __restrict__ unq,
    const float* __restrict__ xtmp,
    const unsigned int* __restrict__ segmax, const float* __restrict__ ss, int N) {
    long t = (long)blockIdx.x * 256 + threadIdx.x;
    long p = t >> 4;
    int qq = (int)(t & 15);
    if (p >= N) return;
    const float4* ss4 = (const float4*)ss;
    float4 sc4 = ss4[qq], sh4 = ss4[16 + qq];

    // left: y = relu(sc*x + sh) from dense xtmp
    f4v x4 = *((const f4v*)xtmp + p * 16 + qq);
    f4v y4;
    y4.x = fmaxf(fmaf(x4.x, sc4.x, sh4.x), 0.f);
    y4.y = fmaxf(fmaf(x4.y, sc4.y, sh4.y), 0.f);
    y4.z = fmaxf(fmaf(x4.z, sc4.z, sh4.z), 0.f);
    y4.w = fmaxf(fmaf(x4.w, sc4.w, sh4.w), 0.f);
    __builtin_nontemporal_store(y4, (f4v*)out + p * 32 + qq);

    // right: decode segmax(raw x), apply same monotone map (exact: same fma as the argmax point)
    int seg = unq[p];
    uint4 m4 = ((const uint4*)segmax)[(long)seg * 16 + qq];
    f4v z4;
    z4.x = fmaxf(fmaf(dec_f(m4.x), sc4.x, sh4.x), 0.f);
    z4.y = fmaxf(fmaf(dec_f(m4.y), sc4.y, sh4.y), 0.f);
    z4.z = fmaxf(fmaf(dec_f(m4.z), sc4.z, sh4.z), 0.f);
    z4.w = fmaxf(fmaf(dec_f(m4.w), sc4.w, sh4.w), 0.f);
    __builtin_nontemporal_store(z4, (f4v*)out + p * 32 + 16 + qq);
}

extern "C" void kernel_launch(void* const* d_in, const int* in_sizes, int n_in,
                              void* d_out, int out_size, void* d_ws, size_t ws_size,
                              hipStream_t stream) {
    const float* in    = (const float*)d_in[0];
    const float* W     = (const float*)d_in[1];
    const float* gamma = (const float*)d_in[2];
    const float* beta  = (const float*)d_in[3];
    const void*  unq   = d_in[4];
    float* out = (float*)d_out;

    const int N   = in_sizes[0] / 64;
    const int NB  = (N + 127) / 128;
    const int NBS = 4 * NB;

    char* ws = (char*)d_ws;
    unsigned int* segmax = (unsigned int*)ws;                    // 10.24 MB (encoded floats)
    size_t off = (size_t)NUM_SEG * 64 * 4;
    float* sums = (float*)(ws + off); off += (size_t)64 * NBS * 4;
    float* sqs  = (float*)(ws + off); off += (size_t)64 * NBS * 4;
    float* ss   = (float*)(ws + off); off += 512;
    int*   unq32= (int*)(ws + off);   off += (size_t)N * 4;
    off = (off + 255) & ~(size_t)255;
    float* xtmp = (float*)(ws + off); off += (size_t)N * 64 * 4; // 256 MB dense raw-x

    const int n4 = NUM_SEG * 64 / 4;
    const int gprep = max((N + 255) / 256, (n4 + 255) / 256);
    k_prep<<<gprep, 256, 0, stream>>>(unq, N, unq32, (float4*)segmax, n4);
    k1_mfma<<<NB, 256, 0, stream>>>(in, W, unq32, xtmp, sums, sqs, segmax, N, NBS);
    k2_stats<<<64, 256, 0, stream>>>(sums, sqs, gamma, beta, ss, N, NBS);
    k4_final<<<(int)(((long)N * 16 + 255) / 256), 256, 0, stream>>>(out, unq32, xtmp, segmax, ss, N);
}